// Round 17
// baseline (415.997 us; speedup 1.0000x reference)
//
#include <hip/hip_runtime.h>
#include <hip/hip_fp16.h>
#include <math.h>

// GIN on MI355X. N=100000, E=1600000, F=H=64, C=10, diameter=6 (fixed).
// R32 (from R31=393.5us): R31 (+14% waves -> -2us) proved the gather is
//   THROUGHPUT-saturated (cache-return bytes), not latency-bound. Fixed
//   32-slot reads waste half the bytes at avg deg 16 (sentinel rows are
//   L1-hit but still 128B each through the return path). Now:
//   (a) degree-predicated gather: slots 0-15 always (1 int2 idx + 2 row
//       loads); slots 16-31 only if d>16 (wave-uniform branch, P~0.43);
//       d>32 tail unchanged. Avg slots 32->~23 (-28% return bytes).
//       Bit-identical (skipped slots were -INF no-ops). R15's variable-
//       LOOP lesson doesn't apply: arms are straight-line, trip fixed.
//   (b) precomputed fp16 W^T: prep_k blocks 0-15 convert proc_w once to
//       ws; gin staging = 576x16B vector copy (was 16 scalar load+f2h+
//       ds_write per thread) x6 steps. Same f2h values -> bit-identical.
//   Keep (256,8) from R31 (no spill; fewer live regs now).
// R30: vectorized epilogue store (2KB contig -> 2x dwordx4): -2us.
// R27/R31: occupancy ladder 6->7 (-24.8us) ->8 (-2us, saturation found).
// R26: encoder on the gin MFMA path (mlp_phase shared): 22 -> ~14us.
// R22: decoder fused into 6th GIN step (k-sliced decode): -41.6us.
// R21: pad_fill deleted (poison -> uclamp -> -INF sentinel); prep merged.
// R16: wide gather 8 lanes/row x dwordx4 (1KB/instr).
// Proven-dead ends: shfl broadcast (R24), fat-kernel fusion under scatter
//   (R19/R23), cursor padding (R18), int4 src sweep (R20), unroll 3 (R20).
//  Kept: fp16 storage, v_pk_max_f16, mfma_f32_16x16x32_f16 (C/D
//  col=lane&15,row=quad*4+reg), CSR CAP=64, XCD scatter, -INF sentinel.

#define NPW 8      // (legacy) encoder nodes/wave in the old fp32 path
#define NPG 16     // nodes/wave for MFMA kernels; block = 4 waves = 64 nodes
#define CAP 64     // fixed CSR slots per node

typedef unsigned short ushort_t;
typedef unsigned int uint_t;
typedef _Float16 half8 __attribute__((ext_vector_type(8)));
typedef float floatx4 __attribute__((ext_vector_type(4)));
typedef uint_t uintx4 __attribute__((ext_vector_type(4)));

__device__ __forceinline__ uint_t pkmax(uint_t a, uint_t b) {
    uint_t r;
    asm volatile("v_pk_max_f16 %0, %1, %2" : "=v"(r) : "v"(a), "v"(b));
    return r;
}
__device__ __forceinline__ uintx4 pkmax4(uintx4 a, uintx4 b) {
    uintx4 r;
    r.x = pkmax(a.x, b.x);
    r.y = pkmax(a.y, b.y);
    r.z = pkmax(a.z, b.z);
    r.w = pkmax(a.w, b.w);
    return r;
}
__device__ __forceinline__ uintx4 shmax4(uintx4 m, int msk) {
    uintx4 t;
    t.x = (uint_t)__shfl_xor((int)m.x, msk);
    t.y = (uint_t)__shfl_xor((int)m.y, msk);
    t.z = (uint_t)__shfl_xor((int)m.z, msk);
    t.w = (uint_t)__shfl_xor((int)m.w, msk);
    return pkmax4(m, t);
}
__device__ __forceinline__ ushort_t f2h(float x) {
    return __half_as_ushort(__float2half_rn(x));
}
__device__ __forceinline__ float h2f_lo(uint_t u) {
    return __half2float(__ushort_as_half((ushort_t)(u & 0xFFFF)));
}
__device__ __forceinline__ float h2f_hi(uint_t u) {
    return __half2float(__ushort_as_half((ushort_t)(u >> 16)));
}
// unsigned clamp: any index > n (incl. 0xAAAAAAAA poison, negative) -> n
__device__ __forceinline__ int uclamp(int i, int n) {
    uint_t u = (uint_t)i, un = (uint_t)n;
    return (int)(u < un ? u : un);
}

// ---------- prep: zero cursors + sentinel rows + fp16 W^T precompute ----
__global__ void prep_k(int* __restrict__ cur, int n,
                       ushort_t* __restrict__ ha, ushort_t* __restrict__ hb,
                       const float* __restrict__ w, ushort_t* __restrict__ wtp) {
    int i = blockIdx.x * blockDim.x + threadIdx.x;
    if (i < n) cur[i] = 0;
    if (blockIdx.x == 0 && threadIdx.x < 64) {
        ha[(size_t)n * 64 + threadIdx.x] = 0xFC00;
        hb[(size_t)n * 64 + threadIdx.x] = 0xFC00;
    }
    // blocks 0..15: wtp[nn*72+k] = fp16(proc_w[k*64+nn]) (once per call)
    if (i < 4096) {
        int k = i >> 6, nn = i & 63;
        wtp[nn * 72 + k] = f2h(w[i]);
    }
}

// ---------- XCD-partitioned scatter into fixed-stride CSR (R16) ----------
// Atomic/latency bound (~75us floor). Must keep 8-VGPR/0-LDS envelope:
// R18 pad, R20 int4, R19/R23 fusion all regressed. Do not touch.
__global__ __launch_bounds__(256) void scatter_xcd(const int* __restrict__ src,
                                                   const int* __restrict__ dst,
                                                   int E, int n,
                                                   int* __restrict__ cursor,
                                                   int* __restrict__ csr_src) {
    int part = blockIdx.x & 7;
    int bip = blockIdx.x >> 3;
    int nGroups = gridDim.x >> 3;
    int lo = (int)(((long long)part * n) >> 3);
    int hi = (int)(((long long)(part + 1) * n) >> 3);
    int stride = nGroups * blockDim.x;
    for (int i = bip * blockDim.x + threadIdx.x; i < E; i += stride) {
        int d = __builtin_nontemporal_load(&dst[i]);
        if (d >= lo && d < hi) {
            int s = __builtin_nontemporal_load(&src[i]);
            int pos = atomicAdd(&cursor[d], 1);
            if (pos < CAP) csr_src[(size_t)d * CAP + pos] = s;
        }
    }
}

// ---------- shared MFMA MLP phase: myhs rows @ Wt + bias -> myhs ----------
// A[m][k]=myhs row m; B[k][n]=Wt[n][k]; frags are contiguous 16B:
// [row=lane&15][k = kt*32 + (lane>>4)*8 + j]. C row(node)=quad*4+i,
// col(feature)=nt*16+m. Used by encode_mfma_k, gin16_k, gin16d_k.
__device__ __forceinline__ void mlp_phase(const ushort_t* __restrict__ Wt,
                                          const float* __restrict__ bias,
                                          ushort_t* __restrict__ myhs,
                                          int lane) {
    int m = lane & 15, quad = lane >> 4;
    float b0 = bias[m], b1 = bias[16 + m], b2 = bias[32 + m], b3 = bias[48 + m];
    floatx4 c0 = {0.f, 0.f, 0.f, 0.f}, c1 = c0, c2 = c0, c3 = c0;
#pragma unroll
    for (int kt = 0; kt < 2; kt++) {
        half8 a = *(const half8*)&myhs[m * 72 + kt * 32 + quad * 8];
        half8 w0 = *(const half8*)&Wt[(m) * 72 + kt * 32 + quad * 8];
        half8 w1 = *(const half8*)&Wt[(16 + m) * 72 + kt * 32 + quad * 8];
        half8 w2 = *(const half8*)&Wt[(32 + m) * 72 + kt * 32 + quad * 8];
        half8 w3 = *(const half8*)&Wt[(48 + m) * 72 + kt * 32 + quad * 8];
        c0 = __builtin_amdgcn_mfma_f32_16x16x32_f16(a, w0, c0, 0, 0, 0);
        c1 = __builtin_amdgcn_mfma_f32_16x16x32_f16(a, w1, c1, 0, 0, 0);
        c2 = __builtin_amdgcn_mfma_f32_16x16x32_f16(a, w2, c2, 0, 0, 0);
        c3 = __builtin_amdgcn_mfma_f32_16x16x32_f16(a, w3, c3, 0, 0, 0);
    }
#pragma unroll
    for (int i = 0; i < 4; i++) {
        int row = quad * 4 + i;
        myhs[row * 72 + m]      = f2h(c0[i] + b0);
        myhs[row * 72 + 16 + m] = f2h(c1[i] + b1);
        myhs[row * 72 + 32 + m] = f2h(c2[i] + b2);
        myhs[row * 72 + 48 + m] = f2h(c3[i] + b3);
    }
}

// ---------- vectorized epilogue store: 16 rows (2KB contig) as 2x16B/lane
__device__ __forceinline__ void store_rows(const ushort_t* __restrict__ myhs,
                                           ushort_t* __restrict__ h2out,
                                           int base, int lane, int n) {
    int r0 = lane >> 3;          // row within the 8-row half
    int c8 = (lane & 7) * 8;     // short offset within a row
#pragma unroll
    for (int j = 0; j < 2; j++) {
        int row = j * 8 + r0;
        int node = base + row;
        if (node < n) {
            uintx4 v = *(const uintx4*)&myhs[row * 72 + c8];
            *(uintx4*)&h2out[(size_t)node * 64 + c8] = v;
        }
    }
}

// ---------- staged Wt copy from precomputed ws buffer (9216B, 16B/instr) --
__device__ __forceinline__ void stage_wt(const ushort_t* __restrict__ wtp,
                                         ushort_t* __restrict__ Wt) {
    const uintx4* s4 = (const uintx4*)wtp;
    uintx4* d4 = (uintx4*)Wt;
    for (int i = threadIdx.x; i < 576; i += 256) d4[i] = s4[i];
}

// ---------- encoder: h = fp16(x) @ enc_w + enc_b via MFMA (R26) ----------
// gin16_k minus the gather: stage x rows fp16 into myhs, shared MFMA MLP,
// vectorized store. x->fp16 is the only new quantization. (Runs once;
// keeps its own enc_w conversion.)
__global__ __launch_bounds__(256, 8) void encode_mfma_k(const float* __restrict__ x,
                                                        const float* __restrict__ w,
                                                        const float* __restrict__ b,
                                                        ushort_t* __restrict__ h2,
                                                        int n) {
    __shared__ __align__(16) ushort_t Wt[64 * 72];       // W^T fp16, row stride 72
    __shared__ __align__(16) ushort_t hs2[4][NPG * 72];  // per-wave rows fp16

    // stage W transposed: Wt[ncol][k] = fp16(w[k][ncol])
    for (int i = threadIdx.x; i < 4096; i += 256) {
        int k = i >> 6, nn = i & 63;
        Wt[nn * 72 + k] = f2h(w[i]);
    }
    __syncthreads();

    int wv = threadIdx.x >> 6, lane = threadIdx.x & 63;
    int base = (blockIdx.x * 4 + wv) * NPG;
    ushort_t* myhs = hs2[wv];

    // stage 16 x-rows as fp16 (coalesced 4B/lane reads; 2B/lane LDS writes
    // = 2 lanes/bank, conflict-free). Invalid rows zeroed (outputs unused).
#pragma unroll
    for (int r = 0; r < NPG; r++) {
        int node = base + r;
        myhs[r * 72 + lane] =
            (node < n) ? f2h(x[(size_t)node * 64 + lane]) : (ushort_t)0;
    }
    // no barrier: myhs is wave-private (compiler orders ds_write->ds_read).

    mlp_phase(Wt, b, myhs, lane);
    store_rows(myhs, h2, base, lane, n);
}

// ---------- GIN gather body: degree-predicated (R32) ----------
// Slots 0-15 always (1 int2 idx + 2 row loads); 16-31 iff d>16; 32-63 iff
// d>32 (both wave-uniform). Skipped slots were sentinel -INF no-ops ->
// bit-identical to the fixed-32 gather, ~28% fewer cache-return bytes.
__device__ __forceinline__ void gin_gather(const ushort_t* __restrict__ h2in,
                                           const int* __restrict__ degcur,
                                           const int* __restrict__ csr_src,
                                           ushort_t* __restrict__ myhs,
                                           int base, int lane, int n) {
    int f8 = lane & 7;          // uintx4 (16B) index within a 128B row
    int sub3 = lane >> 3;       // 0..7: slot-pair subgroup
    const uintx4* hq = (const uintx4*)h2in;   // row = 8 uintx4

#pragma unroll 2
    for (int rp = 0; rp < NPG; rp++) {
        int node = base + rp;
        bool v = node < n;
        int d = v ? degcur[node] : 0;
        d = (d > CAP) ? CAP : d;
        const int2* ip2 = (const int2*)&csr_src[(size_t)(v ? node : 0) * CAP];
        int2 i0 = ip2[sub3];                  // slots 2s, 2s+1 in [0,16)
        uintx4 a0 = hq[(size_t)uclamp(i0.x, n) * 8 + f8];
        uintx4 a1 = hq[(size_t)uclamp(i0.y, n) * 8 + f8];
        uintx4 m = pkmax4(a0, a1);
        if (d > 16) {                         // wave-uniform (P~0.43)
            int2 i1 = ip2[8 + sub3];          // slots 16..31
            uintx4 b0 = hq[(size_t)uclamp(i1.x, n) * 8 + f8];
            uintx4 b1 = hq[(size_t)uclamp(i1.y, n) * 8 + f8];
            m = pkmax4(m, pkmax4(b0, b1));
            if (d > 32) {                     // rare tail: slots 32..63
                int4 i2 = ((const int4*)ip2)[8 + sub3];
                uintx4 c0 = hq[(size_t)uclamp(i2.x, n) * 8 + f8];
                uintx4 c1 = hq[(size_t)uclamp(i2.y, n) * 8 + f8];
                uintx4 c2 = hq[(size_t)uclamp(i2.z, n) * 8 + f8];
                uintx4 c3 = hq[(size_t)uclamp(i2.w, n) * 8 + f8];
                m = pkmax4(m, pkmax4(pkmax4(c0, c1), pkmax4(c2, c3)));
            }
        }
        // butterfly across the 8 subgroups (lane bits 3,4,5); LDS pipe.
        m = shmax4(m, 8);
        m = shmax4(m, 16);
        m = shmax4(m, 32);
        if (sub3 == 0 && v) {   // 8 lanes hold the full 64-feature max
            uintx4 s = hq[(size_t)node * 8 + f8];
            float r0 = h2f_lo(s.x), r1 = h2f_hi(s.x);
            float r2 = h2f_lo(s.y), r3 = h2f_hi(s.y);
            float r4 = h2f_lo(s.z), r5 = h2f_hi(s.z);
            float r6 = h2f_lo(s.w), r7 = h2f_hi(s.w);
            if (d > 0) {
                r0 += h2f_lo(m.x); r1 += h2f_hi(m.x);
                r2 += h2f_lo(m.y); r3 += h2f_hi(m.y);
                r4 += h2f_lo(m.z); r5 += h2f_hi(m.z);
                r6 += h2f_lo(m.w); r7 += h2f_hi(m.w);
            }
            uintx4 o;
            o.x = (uint_t)f2h(r0) | ((uint_t)f2h(r1) << 16);
            o.y = (uint_t)f2h(r2) | ((uint_t)f2h(r3) << 16);
            o.z = (uint_t)f2h(r4) | ((uint_t)f2h(r5) << 16);
            o.w = (uint_t)f2h(r6) | ((uint_t)f2h(r7) << 16);
            *(uintx4*)&myhs[rp * 72 + f8 * 8] = o;   // 16B aligned (144rp+16f8)
        }
    }
    // no barrier: myhs is wave-private.
}

// ---------- GIN step (steps 1-5): gather + MLP + vectorized store ----------
__global__ __launch_bounds__(256, 8) void gin16_k(const ushort_t* __restrict__ h2in,
                                                  ushort_t* __restrict__ h2out,
                                                  const int* __restrict__ degcur,
                                                  const int* __restrict__ csr_src,
                                                  const ushort_t* __restrict__ wtp,
                                                  const float* __restrict__ bias,
                                                  int n) {
    __shared__ __align__(16) ushort_t Wt[64 * 72];       // W^T fp16, row stride 72
    __shared__ __align__(16) ushort_t hs2[4][NPG * 72];  // per-wave t rows fp16

    stage_wt(wtp, Wt);
    __syncthreads();

    int wv = threadIdx.x >> 6, lane = threadIdx.x & 63;
    int base = (blockIdx.x * 4 + wv) * NPG;
    ushort_t* myhs = hs2[wv];

    gin_gather(h2in, degcur, csr_src, myhs, base, lane, n);
    mlp_phase(Wt, bias, myhs, lane);
    store_rows(myhs, h2out, base, lane, n);
}

// ---------- GIN step 6 + fused decoder (R22) ----------
// Stays (256,7): 22528B LDS caps at 7 blocks/CU regardless of VGPR.
__global__ __launch_bounds__(256, 7) void gin16d_k(const ushort_t* __restrict__ h2in,
                                                   const int* __restrict__ degcur,
                                                   const int* __restrict__ csr_src,
                                                   const ushort_t* __restrict__ wtp,
                                                   const float* __restrict__ bias,
                                                   const float* __restrict__ dw,
                                                   const float* __restrict__ db,
                                                   float* __restrict__ out,
                                                   int n) {
    __shared__ __align__(16) ushort_t Wt[64 * 72];       // W^T fp16, row stride 72
    __shared__ __align__(16) ushort_t hs2[4][NPG * 72];  // per-wave t rows fp16
    __shared__ __align__(16) float dws[64 * 16];         // dec_w [k][c], c padded to 16

    stage_wt(wtp, Wt);
    for (int i = threadIdx.x; i < 1024; i += 256) {
        int k = i >> 4, c = i & 15;
        dws[i] = (c < 10) ? dw[k * 10 + c] : 0.0f;
    }
    __syncthreads();

    int wv = threadIdx.x >> 6, lane = threadIdx.x & 63;
    int base = (blockIdx.x * 4 + wv) * NPG;
    ushort_t* myhs = hs2[wv];

    gin_gather(h2in, degcur, csr_src, myhs, base, lane, n);
    mlp_phase(Wt, bias, myhs, lane);

    // ---- fused decode (myhs rows are wave-private; no barrier needed) ----
    int m = lane & 15, quad = lane >> 4;
    float l[10];
#pragma unroll
    for (int c = 0; c < 10; c++) l[c] = 0.0f;
#pragma unroll
    for (int kk = 0; kk < 16; kk++) {
        int k = quad * 16 + kk;
        float hv = __half2float(__ushort_as_half(myhs[m * 72 + k]));
        const float* wr = &dws[k * 16];
        float4 w0 = *(const float4*)wr;
        float4 w1 = *(const float4*)(wr + 4);
        float2 w2 = *(const float2*)(wr + 8);
        l[0] = fmaf(hv, w0.x, l[0]);
        l[1] = fmaf(hv, w0.y, l[1]);
        l[2] = fmaf(hv, w0.z, l[2]);
        l[3] = fmaf(hv, w0.w, l[3]);
        l[4] = fmaf(hv, w1.x, l[4]);
        l[5] = fmaf(hv, w1.y, l[5]);
        l[6] = fmaf(hv, w1.z, l[6]);
        l[7] = fmaf(hv, w1.w, l[7]);
        l[8] = fmaf(hv, w2.x, l[8]);
        l[9] = fmaf(hv, w2.y, l[9]);
    }
#pragma unroll
    for (int c = 0; c < 10; c++) {
        l[c] += __shfl_xor(l[c], 16);
        l[c] += __shfl_xor(l[c], 32);
    }
    if (quad == 0) {
        int node = base + m;
        if (node < n) {
            float mx = -INFINITY;
#pragma unroll
            for (int c = 0; c < 10; c++) { l[c] += db[c]; mx = fmaxf(mx, l[c]); }
            float sum = 0.0f;
#pragma unroll
            for (int c = 0; c < 10; c++) sum += expf(l[c] - mx);
            float lse = mx + logf(sum);
#pragma unroll
            for (int c = 0; c < 10; c++) out[(size_t)node * 10 + c] = l[c] - lse;
        }
    }
}

extern "C" void kernel_launch(void* const* d_in, const int* in_sizes, int n_in,
                              void* d_out, int out_size, void* d_ws, size_t ws_size,
                              hipStream_t stream) {
    const float* x     = (const float*)d_in[0];
    const int*   ei    = (const int*)d_in[1];
    // d_in[2] = diameter (always 6; loop count must be static for graph capture)
    const float* enc_w = (const float*)d_in[3];
    const float* enc_b = (const float*)d_in[4];
    const float* proc_w = (const float*)d_in[5];
    const float* proc_b = (const float*)d_in[6];
    const float* dec_w = (const float*)d_in[7];
    const float* dec_b = (const float*)d_in[8];
    float* out = (float*)d_out;

    const int n = in_sizes[0] / 64;
    const int E = in_sizes[1] / 2;
    const int* src = ei;
    const int* dst = ei + E;

    // workspace carve (ws re-poisoned every call -> rebuild everything)
    // fp16 activations: n+1 rows, row n = -INF sentinel
    char* p = (char*)d_ws;
    ushort_t* h_a = (ushort_t*)p;    p += (size_t)(n + 1) * 64 * sizeof(ushort_t);
    ushort_t* h_b = (ushort_t*)p;    p += (size_t)(n + 1) * 64 * sizeof(ushort_t);
    int* cur = (int*)p;              p += (size_t)n * sizeof(int);
    int* csr = (int*)p;              p += (size_t)n * CAP * sizeof(int);
    ushort_t* wtp = (ushort_t*)p;    p += (size_t)64 * 72 * sizeof(ushort_t);

    const int gN = (n + 255) / 256;
    const int gTileG = (n + 4 * NPG - 1) / (4 * NPG);

    // prep (zero cursors + sentinel rows + fp16 W^T), XCD ticket scatter
    prep_k<<<gN, 256, 0, stream>>>(cur, n, h_a, h_b, proc_w, wtp);
    scatter_xcd<<<2048, 256, 0, stream>>>(src, dst, E, n, cur, csr);

    // encoder (MFMA path, same tile structure as gin)
    encode_mfma_k<<<gTileG, 256, 0, stream>>>(x, enc_w, enc_b, h_a, n);

    // 5 full GIN steps, ping-pong
    ushort_t* hi = h_a;
    ushort_t* ho = h_b;
    for (int it = 0; it < 5; it++) {
        gin16_k<<<gTileG, 256, 0, stream>>>(hi, ho, cur, csr, wtp, proc_b, n);
        ushort_t* t = hi; hi = ho; ho = t;
    }

    // 6th GIN step with fused decoder (writes out directly)
    gin16d_k<<<gTileG, 256, 0, stream>>>(hi, cur, csr, wtp, proc_b,
                                         dec_w, dec_b, out, n);
}

// Round 18
// 395.877 us; speedup vs baseline: 1.0508x; 1.0508x over previous
//
#include <hip/hip_runtime.h>
#include <hip/hip_fp16.h>
#include <math.h>

// GIN on MI355X. N=100000, E=1600000, F=H=64, C=10, diameter=6 (fixed).
// R33 (consolidation; from R32=416us regression, best=R31=393.5us):
//   revert the predicated gather, keep the untainted R32 pieces.
//   R32 post-mortem: int2 idx split DOUBLED load instrs on the
//   always-executed half (2 rows/instr vs R16's 4) and the nested
//   branches broke cross-body pipelining; sentinel loads were near-free
//   (8 lanes broadcast-hit one L1 line) so the "wasted bytes" theory was
//   wrong. Cache-return saturation REFUTED; gather's 1.5 TB/s at 8
//   blocks/CU is its structural operating point (ladder closed: R27 +1
//   wave=-25us, R31 +1 wave=-2us, R32 fewer bytes=+22us).
//   Kept from R32: wtp precompute (f2h(proc_w) once in prep, gin staging
//   = 576x16B copies; bit-identical). Kept: store_rows (R30), (256,8)
//   on gin16_k/encode (R31), (256,7) on gin16d_k.
// R26: encoder on the gin MFMA path (mlp_phase shared): 22 -> ~14us.
// R22: decoder fused into 6th GIN step (k-sliced decode): -41.6us.
// R21: pad_fill deleted (poison -> uclamp -> -INF sentinel); prep merged.
// R16: wide gather 8 lanes/row x dwordx4 (1KB/instr), int4 idx covers
//   32 slots/node; 3-level shfl_xor butterfly (8/16/32).
// Proven-dead ends: shfl broadcast (R24), fat-kernel fusion under scatter
//   (R19/R23), cursor padding (R18), int4 src sweep (R20), unroll 3
//   (R20), predicated gather (R32).
//  Kept: fp16 storage, v_pk_max_f16, mfma_f32_16x16x32_f16 (C/D
//  col=lane&15,row=quad*4+reg), CSR CAP=64, XCD scatter, -INF sentinel.

#define NPW 8      // (legacy) encoder nodes/wave in the old fp32 path
#define NPG 16     // nodes/wave for MFMA kernels; block = 4 waves = 64 nodes
#define CAP 64     // fixed CSR slots per node

typedef unsigned short ushort_t;
typedef unsigned int uint_t;
typedef _Float16 half8 __attribute__((ext_vector_type(8)));
typedef float floatx4 __attribute__((ext_vector_type(4)));
typedef uint_t uintx4 __attribute__((ext_vector_type(4)));

__device__ __forceinline__ uint_t pkmax(uint_t a, uint_t b) {
    uint_t r;
    asm volatile("v_pk_max_f16 %0, %1, %2" : "=v"(r) : "v"(a), "v"(b));
    return r;
}
__device__ __forceinline__ uintx4 pkmax4(uintx4 a, uintx4 b) {
    uintx4 r;
    r.x = pkmax(a.x, b.x);
    r.y = pkmax(a.y, b.y);
    r.z = pkmax(a.z, b.z);
    r.w = pkmax(a.w, b.w);
    return r;
}
__device__ __forceinline__ uintx4 shmax4(uintx4 m, int msk) {
    uintx4 t;
    t.x = (uint_t)__shfl_xor((int)m.x, msk);
    t.y = (uint_t)__shfl_xor((int)m.y, msk);
    t.z = (uint_t)__shfl_xor((int)m.z, msk);
    t.w = (uint_t)__shfl_xor((int)m.w, msk);
    return pkmax4(m, t);
}
__device__ __forceinline__ ushort_t f2h(float x) {
    return __half_as_ushort(__float2half_rn(x));
}
__device__ __forceinline__ float h2f_lo(uint_t u) {
    return __half2float(__ushort_as_half((ushort_t)(u & 0xFFFF)));
}
__device__ __forceinline__ float h2f_hi(uint_t u) {
    return __half2float(__ushort_as_half((ushort_t)(u >> 16)));
}
// unsigned clamp: any index > n (incl. 0xAAAAAAAA poison, negative) -> n
__device__ __forceinline__ int uclamp(int i, int n) {
    uint_t u = (uint_t)i, un = (uint_t)n;
    return (int)(u < un ? u : un);
}

// ---------- prep: zero cursors + sentinel rows + fp16 W^T precompute ----
__global__ void prep_k(int* __restrict__ cur, int n,
                       ushort_t* __restrict__ ha, ushort_t* __restrict__ hb,
                       const float* __restrict__ w, ushort_t* __restrict__ wtp) {
    int i = blockIdx.x * blockDim.x + threadIdx.x;
    if (i < n) cur[i] = 0;
    if (blockIdx.x == 0 && threadIdx.x < 64) {
        ha[(size_t)n * 64 + threadIdx.x] = 0xFC00;
        hb[(size_t)n * 64 + threadIdx.x] = 0xFC00;
    }
    // blocks 0..15: wtp[nn*72+k] = fp16(proc_w[k*64+nn]) (once per call)
    if (i < 4096) {
        int k = i >> 6, nn = i & 63;
        wtp[nn * 72 + k] = f2h(w[i]);
    }
}

// ---------- XCD-partitioned scatter into fixed-stride CSR (R16) ----------
// Atomic/latency bound (~75us floor). Must keep 8-VGPR/0-LDS envelope:
// R18 pad, R20 int4, R19/R23 fusion all regressed. Do not touch.
__global__ __launch_bounds__(256) void scatter_xcd(const int* __restrict__ src,
                                                   const int* __restrict__ dst,
                                                   int E, int n,
                                                   int* __restrict__ cursor,
                                                   int* __restrict__ csr_src) {
    int part = blockIdx.x & 7;
    int bip = blockIdx.x >> 3;
    int nGroups = gridDim.x >> 3;
    int lo = (int)(((long long)part * n) >> 3);
    int hi = (int)(((long long)(part + 1) * n) >> 3);
    int stride = nGroups * blockDim.x;
    for (int i = bip * blockDim.x + threadIdx.x; i < E; i += stride) {
        int d = __builtin_nontemporal_load(&dst[i]);
        if (d >= lo && d < hi) {
            int s = __builtin_nontemporal_load(&src[i]);
            int pos = atomicAdd(&cursor[d], 1);
            if (pos < CAP) csr_src[(size_t)d * CAP + pos] = s;
        }
    }
}

// ---------- shared MFMA MLP phase: myhs rows @ Wt + bias -> myhs ----------
// A[m][k]=myhs row m; B[k][n]=Wt[n][k]; frags are contiguous 16B:
// [row=lane&15][k = kt*32 + (lane>>4)*8 + j]. C row(node)=quad*4+i,
// col(feature)=nt*16+m. Used by encode_mfma_k, gin16_k, gin16d_k.
__device__ __forceinline__ void mlp_phase(const ushort_t* __restrict__ Wt,
                                          const float* __restrict__ bias,
                                          ushort_t* __restrict__ myhs,
                                          int lane) {
    int m = lane & 15, quad = lane >> 4;
    float b0 = bias[m], b1 = bias[16 + m], b2 = bias[32 + m], b3 = bias[48 + m];
    floatx4 c0 = {0.f, 0.f, 0.f, 0.f}, c1 = c0, c2 = c0, c3 = c0;
#pragma unroll
    for (int kt = 0; kt < 2; kt++) {
        half8 a = *(const half8*)&myhs[m * 72 + kt * 32 + quad * 8];
        half8 w0 = *(const half8*)&Wt[(m) * 72 + kt * 32 + quad * 8];
        half8 w1 = *(const half8*)&Wt[(16 + m) * 72 + kt * 32 + quad * 8];
        half8 w2 = *(const half8*)&Wt[(32 + m) * 72 + kt * 32 + quad * 8];
        half8 w3 = *(const half8*)&Wt[(48 + m) * 72 + kt * 32 + quad * 8];
        c0 = __builtin_amdgcn_mfma_f32_16x16x32_f16(a, w0, c0, 0, 0, 0);
        c1 = __builtin_amdgcn_mfma_f32_16x16x32_f16(a, w1, c1, 0, 0, 0);
        c2 = __builtin_amdgcn_mfma_f32_16x16x32_f16(a, w2, c2, 0, 0, 0);
        c3 = __builtin_amdgcn_mfma_f32_16x16x32_f16(a, w3, c3, 0, 0, 0);
    }
#pragma unroll
    for (int i = 0; i < 4; i++) {
        int row = quad * 4 + i;
        myhs[row * 72 + m]      = f2h(c0[i] + b0);
        myhs[row * 72 + 16 + m] = f2h(c1[i] + b1);
        myhs[row * 72 + 32 + m] = f2h(c2[i] + b2);
        myhs[row * 72 + 48 + m] = f2h(c3[i] + b3);
    }
}

// ---------- vectorized epilogue store: 16 rows (2KB contig) as 2x16B/lane
__device__ __forceinline__ void store_rows(const ushort_t* __restrict__ myhs,
                                           ushort_t* __restrict__ h2out,
                                           int base, int lane, int n) {
    int r0 = lane >> 3;          // row within the 8-row half
    int c8 = (lane & 7) * 8;     // short offset within a row
#pragma unroll
    for (int j = 0; j < 2; j++) {
        int row = j * 8 + r0;
        int node = base + row;
        if (node < n) {
            uintx4 v = *(const uintx4*)&myhs[row * 72 + c8];
            *(uintx4*)&h2out[(size_t)node * 64 + c8] = v;
        }
    }
}

// ---------- staged Wt copy from precomputed ws buffer (9216B, 16B/instr) --
__device__ __forceinline__ void stage_wt(const ushort_t* __restrict__ wtp,
                                         ushort_t* __restrict__ Wt) {
    const uintx4* s4 = (const uintx4*)wtp;
    uintx4* d4 = (uintx4*)Wt;
    for (int i = threadIdx.x; i < 576; i += 256) d4[i] = s4[i];
}

// ---------- encoder: h = fp16(x) @ enc_w + enc_b via MFMA (R26) ----------
// gin16_k minus the gather: stage x rows fp16 into myhs, shared MFMA MLP,
// vectorized store. x->fp16 is the only new quantization. (Runs once;
// keeps its own enc_w conversion.)
__global__ __launch_bounds__(256, 8) void encode_mfma_k(const float* __restrict__ x,
                                                        const float* __restrict__ w,
                                                        const float* __restrict__ b,
                                                        ushort_t* __restrict__ h2,
                                                        int n) {
    __shared__ __align__(16) ushort_t Wt[64 * 72];       // W^T fp16, row stride 72
    __shared__ __align__(16) ushort_t hs2[4][NPG * 72];  // per-wave rows fp16

    // stage W transposed: Wt[ncol][k] = fp16(w[k][ncol])
    for (int i = threadIdx.x; i < 4096; i += 256) {
        int k = i >> 6, nn = i & 63;
        Wt[nn * 72 + k] = f2h(w[i]);
    }
    __syncthreads();

    int wv = threadIdx.x >> 6, lane = threadIdx.x & 63;
    int base = (blockIdx.x * 4 + wv) * NPG;
    ushort_t* myhs = hs2[wv];

    // stage 16 x-rows as fp16 (coalesced 4B/lane reads; 2B/lane LDS writes
    // = 2 lanes/bank, conflict-free). Invalid rows zeroed (outputs unused).
#pragma unroll
    for (int r = 0; r < NPG; r++) {
        int node = base + r;
        myhs[r * 72 + lane] =
            (node < n) ? f2h(x[(size_t)node * 64 + lane]) : (ushort_t)0;
    }
    // no barrier: myhs is wave-private (compiler orders ds_write->ds_read).

    mlp_phase(Wt, b, myhs, lane);
    store_rows(myhs, h2, base, lane, n);
}

// ---------- GIN gather body (R16/R31 form): fixed 32-slot wide gather ----
__device__ __forceinline__ void gin_gather(const ushort_t* __restrict__ h2in,
                                           const int* __restrict__ degcur,
                                           const int* __restrict__ csr_src,
                                           ushort_t* __restrict__ myhs,
                                           int base, int lane, int n) {
    int f8 = lane & 7;          // uintx4 (16B) index within a 128B row
    int sub3 = lane >> 3;       // 0..7: slot within the int4-quad batch
    const uintx4* hq = (const uintx4*)h2in;   // row = 8 uintx4

    // One int4 index load (8 subgroups -> 32 slots) + 4 row loads (each
    // instr = 8 rows x 128B = 1KB) cover a whole node for deg<=32
    // (Poisson(16): P(deg>32)~1e-4 -> rare uniform tail branch).
    // Unwritten slots hold ws poison -> uclamp -> sentinel row n (-INF,
    // L1-hot, numerically inert). No pad_fill needed (R19/R20-proven).
    // unroll 2 is the VGPR sweet spot; unroll 3 spilled (R20, +10us/step).
#pragma unroll 2
    for (int rp = 0; rp < NPG; rp++) {
        int node = base + rp;
        bool v = node < n;
        int d = v ? degcur[node] : 0;
        d = (d > CAP) ? CAP : d;
        const int4* ip = (const int4*)&csr_src[(size_t)(v ? node : 0) * CAP];
        int4 i0 = ip[sub3];
        uintx4 a0 = hq[(size_t)uclamp(i0.x, n) * 8 + f8];
        uintx4 a1 = hq[(size_t)uclamp(i0.y, n) * 8 + f8];
        uintx4 a2 = hq[(size_t)uclamp(i0.z, n) * 8 + f8];
        uintx4 a3 = hq[(size_t)uclamp(i0.w, n) * 8 + f8];
        uintx4 m = pkmax4(pkmax4(a0, a1), pkmax4(a2, a3));
        if (d > 32) {  // rare tail: slots 32..63 (wave-uniform branch)
            int4 i1 = ip[8 + sub3];
            uintx4 c0 = hq[(size_t)uclamp(i1.x, n) * 8 + f8];
            uintx4 c1 = hq[(size_t)uclamp(i1.y, n) * 8 + f8];
            uintx4 c2 = hq[(size_t)uclamp(i1.z, n) * 8 + f8];
            uintx4 c3 = hq[(size_t)uclamp(i1.w, n) * 8 + f8];
            m = pkmax4(m, pkmax4(pkmax4(c0, c1), pkmax4(c2, c3)));
        }
        // butterfly across the 8 subgroups (lane bits 3,4,5); LDS pipe,
        // overlaps the next body's VMEM.
        m = shmax4(m, 8);
        m = shmax4(m, 16);
        m = shmax4(m, 32);
        if (sub3 == 0 && v) {   // 8 lanes hold the full 64-feature max
            uintx4 s = hq[(size_t)node * 8 + f8];
            float r0 = h2f_lo(s.x), r1 = h2f_hi(s.x);
            float r2 = h2f_lo(s.y), r3 = h2f_hi(s.y);
            float r4 = h2f_lo(s.z), r5 = h2f_hi(s.z);
            float r6 = h2f_lo(s.w), r7 = h2f_hi(s.w);
            if (d > 0) {
                r0 += h2f_lo(m.x); r1 += h2f_hi(m.x);
                r2 += h2f_lo(m.y); r3 += h2f_hi(m.y);
                r4 += h2f_lo(m.z); r5 += h2f_hi(m.z);
                r6 += h2f_lo(m.w); r7 += h2f_hi(m.w);
            }
            uintx4 o;
            o.x = (uint_t)f2h(r0) | ((uint_t)f2h(r1) << 16);
            o.y = (uint_t)f2h(r2) | ((uint_t)f2h(r3) << 16);
            o.z = (uint_t)f2h(r4) | ((uint_t)f2h(r5) << 16);
            o.w = (uint_t)f2h(r6) | ((uint_t)f2h(r7) << 16);
            *(uintx4*)&myhs[rp * 72 + f8 * 8] = o;   // 16B aligned (144rp+16f8)
        }
    }
    // no barrier: myhs is wave-private.
}

// ---------- GIN step (steps 1-5): gather + MLP + vectorized store ----------
__global__ __launch_bounds__(256, 8) void gin16_k(const ushort_t* __restrict__ h2in,
                                                  ushort_t* __restrict__ h2out,
                                                  const int* __restrict__ degcur,
                                                  const int* __restrict__ csr_src,
                                                  const ushort_t* __restrict__ wtp,
                                                  const float* __restrict__ bias,
                                                  int n) {
    __shared__ __align__(16) ushort_t Wt[64 * 72];       // W^T fp16, row stride 72
    __shared__ __align__(16) ushort_t hs2[4][NPG * 72];  // per-wave t rows fp16

    stage_wt(wtp, Wt);
    __syncthreads();

    int wv = threadIdx.x >> 6, lane = threadIdx.x & 63;
    int base = (blockIdx.x * 4 + wv) * NPG;
    ushort_t* myhs = hs2[wv];

    gin_gather(h2in, degcur, csr_src, myhs, base, lane, n);
    mlp_phase(Wt, bias, myhs, lane);
    store_rows(myhs, h2out, base, lane, n);
}

// ---------- GIN step 6 + fused decoder (R22) ----------
// Stays (256,7): 22528B LDS caps at 7 blocks/CU regardless of VGPR.
__global__ __launch_bounds__(256, 7) void gin16d_k(const ushort_t* __restrict__ h2in,
                                                   const int* __restrict__ degcur,
                                                   const int* __restrict__ csr_src,
                                                   const ushort_t* __restrict__ wtp,
                                                   const float* __restrict__ bias,
                                                   const float* __restrict__ dw,
                                                   const float* __restrict__ db,
                                                   float* __restrict__ out,
                                                   int n) {
    __shared__ __align__(16) ushort_t Wt[64 * 72];       // W^T fp16, row stride 72
    __shared__ __align__(16) ushort_t hs2[4][NPG * 72];  // per-wave t rows fp16
    __shared__ __align__(16) float dws[64 * 16];         // dec_w [k][c], c padded to 16

    stage_wt(wtp, Wt);
    for (int i = threadIdx.x; i < 1024; i += 256) {
        int k = i >> 4, c = i & 15;
        dws[i] = (c < 10) ? dw[k * 10 + c] : 0.0f;
    }
    __syncthreads();

    int wv = threadIdx.x >> 6, lane = threadIdx.x & 63;
    int base = (blockIdx.x * 4 + wv) * NPG;
    ushort_t* myhs = hs2[wv];

    gin_gather(h2in, degcur, csr_src, myhs, base, lane, n);
    mlp_phase(Wt, bias, myhs, lane);

    // ---- fused decode (myhs rows are wave-private; no barrier needed) ----
    int m = lane & 15, quad = lane >> 4;
    float l[10];
#pragma unroll
    for (int c = 0; c < 10; c++) l[c] = 0.0f;
#pragma unroll
    for (int kk = 0; kk < 16; kk++) {
        int k = quad * 16 + kk;
        float hv = __half2float(__ushort_as_half(myhs[m * 72 + k]));
        const float* wr = &dws[k * 16];
        float4 w0 = *(const float4*)wr;
        float4 w1 = *(const float4*)(wr + 4);
        float2 w2 = *(const float2*)(wr + 8);
        l[0] = fmaf(hv, w0.x, l[0]);
        l[1] = fmaf(hv, w0.y, l[1]);
        l[2] = fmaf(hv, w0.z, l[2]);
        l[3] = fmaf(hv, w0.w, l[3]);
        l[4] = fmaf(hv, w1.x, l[4]);
        l[5] = fmaf(hv, w1.y, l[5]);
        l[6] = fmaf(hv, w1.z, l[6]);
        l[7] = fmaf(hv, w1.w, l[7]);
        l[8] = fmaf(hv, w2.x, l[8]);
        l[9] = fmaf(hv, w2.y, l[9]);
    }
#pragma unroll
    for (int c = 0; c < 10; c++) {
        l[c] += __shfl_xor(l[c], 16);
        l[c] += __shfl_xor(l[c], 32);
    }
    if (quad == 0) {
        int node = base + m;
        if (node < n) {
            float mx = -INFINITY;
#pragma unroll
            for (int c = 0; c < 10; c++) { l[c] += db[c]; mx = fmaxf(mx, l[c]); }
            float sum = 0.0f;
#pragma unroll
            for (int c = 0; c < 10; c++) sum += expf(l[c] - mx);
            float lse = mx + logf(sum);
#pragma unroll
            for (int c = 0; c < 10; c++) out[(size_t)node * 10 + c] = l[c] - lse;
        }
    }
}

extern "C" void kernel_launch(void* const* d_in, const int* in_sizes, int n_in,
                              void* d_out, int out_size, void* d_ws, size_t ws_size,
                              hipStream_t stream) {
    const float* x     = (const float*)d_in[0];
    const int*   ei    = (const int*)d_in[1];
    // d_in[2] = diameter (always 6; loop count must be static for graph capture)
    const float* enc_w = (const float*)d_in[3];
    const float* enc_b = (const float*)d_in[4];
    const float* proc_w = (const float*)d_in[5];
    const float* proc_b = (const float*)d_in[6];
    const float* dec_w = (const float*)d_in[7];
    const float* dec_b = (const float*)d_in[8];
    float* out = (float*)d_out;

    const int n = in_sizes[0] / 64;
    const int E = in_sizes[1] / 2;
    const int* src = ei;
    const int* dst = ei + E;

    // workspace carve (ws re-poisoned every call -> rebuild everything)
    // fp16 activations: n+1 rows, row n = -INF sentinel
    char* p = (char*)d_ws;
    ushort_t* h_a = (ushort_t*)p;    p += (size_t)(n + 1) * 64 * sizeof(ushort_t);
    ushort_t* h_b = (ushort_t*)p;    p += (size_t)(n + 1) * 64 * sizeof(ushort_t);
    int* cur = (int*)p;              p += (size_t)n * sizeof(int);
    int* csr = (int*)p;              p += (size_t)n * CAP * sizeof(int);
    ushort_t* wtp = (ushort_t*)p;    p += (size_t)64 * 72 * sizeof(ushort_t);

    const int gN = (n + 255) / 256;
    const int gTileG = (n + 4 * NPG - 1) / (4 * NPG);

    // prep (zero cursors + sentinel rows + fp16 W^T), XCD ticket scatter
    prep_k<<<gN, 256, 0, stream>>>(cur, n, h_a, h_b, proc_w, wtp);
    scatter_xcd<<<2048, 256, 0, stream>>>(src, dst, E, n, cur, csr);

    // encoder (MFMA path, same tile structure as gin)
    encode_mfma_k<<<gTileG, 256, 0, stream>>>(x, enc_w, enc_b, h_a, n);

    // 5 full GIN steps, ping-pong
    ushort_t* hi = h_a;
    ushort_t* ho = h_b;
    for (int it = 0; it < 5; it++) {
        gin16_k<<<gTileG, 256, 0, stream>>>(hi, ho, cur, csr, wtp, proc_b, n);
        ushort_t* t = hi; hi = ho; ho = t;
    }

    // 6th GIN step with fused decoder (writes out directly)
    gin16d_k<<<gTileG, 256, 0, stream>>>(hi, cur, csr, wtp, proc_b,
                                         dec_w, dec_b, out, n);
}